// Round 1
// baseline (825.332 us; speedup 1.0000x reference)
//
#include <hip/hip_runtime.h>
#include <stdint.h>

#define B 8192
#define D 128
#define MARGIN 0.3f
#define EPS 1e-6f
#define HALFN (1u << 25)   // B*B/2 = 2^25

// ---- Threefry-2x32 (JAX-compatible: 20 rounds, 5 key injections) ----
__host__ __device__ __forceinline__ void tf2x32(uint32_t k0, uint32_t k1,
                                                uint32_t x0, uint32_t x1,
                                                uint32_t& o0, uint32_t& o1) {
  uint32_t ks2 = k0 ^ k1 ^ 0x1BD11BDAu;
  uint32_t v0 = x0 + k0, v1 = x1 + k1;
#define RND(r) { v0 += v1; v1 = (v1 << (r)) | (v1 >> (32 - (r))); v1 ^= v0; }
  RND(13) RND(15) RND(26) RND(6)
  v0 += k1;  v1 += ks2 + 1u;
  RND(17) RND(29) RND(16) RND(24)
  v0 += ks2; v1 += k0 + 2u;
  RND(13) RND(15) RND(26) RND(6)
  v0 += k0;  v1 += k1 + 3u;
  RND(17) RND(29) RND(16) RND(24)
  v0 += k1;  v1 += ks2 + 4u;
  RND(13) RND(15) RND(26) RND(6)
  v0 += ks2; v1 += k0 + 5u;
#undef RND
  o0 = v0; o1 = v1;
}

// bits>>9 of the uniform sample at flat position f of a (B,B) jax.random draw.
// Gumbel(-log(-log(u))) is strictly monotone in this value -> argmax equivalence.
__device__ __forceinline__ uint32_t gbits(uint32_t k0, uint32_t k1, uint32_t f) {
  bool lo = f < HALFN;
  uint32_t x0 = lo ? f : f - HALFN;
  uint32_t x1 = lo ? f + HALFN : f;
  uint32_t o0, o1;
  tf2x32(k0, k1, x0, x1, o0, o1);
  return (lo ? o0 : o1) >> 9;
}

// ---- 1. self dot products (diag of emb@emb.T) ----
__global__ void sq_kernel(const float* __restrict__ emb, float* __restrict__ sq) {
  int i = blockIdx.x, t = threadIdx.x;  // 64 threads
  float v0 = emb[i * D + t], v1 = emb[i * D + 64 + t];
  float s = v0 * v0 + v1 * v1;
  #pragma unroll
  for (int off = 32; off > 0; off >>= 1) s += __shfl_down(s, off);
  if (t == 0) sq[i] = s;
}

// ---- 2. positive mining: gumbel-argmax over same-label (j!=i), ap, validity ----
__global__ __launch_bounds__(256) void pos_kernel(
    const float* __restrict__ emb, const int* __restrict__ labels,
    const float* __restrict__ sq, uint32_t kp0, uint32_t kp1,
    int* __restrict__ posx, float* __restrict__ apod, int* __restrict__ validf) {
  __shared__ uint32_t rb[256];
  __shared__ int ri[256];
  __shared__ int rc[256];
  __shared__ float red[128];
  __shared__ int s_pidx;
  int i = blockIdx.x, tid = threadIdx.x;
  int lab = labels[i];
  uint32_t fbase = (uint32_t)i << 13;
  uint32_t bb = 0; int bi = -1; int cnt = 0;
  for (int j = tid; j < B; j += 256) {
    bool same = (labels[j] == lab);
    cnt += same ? 1 : 0;
    if (same && j != i) {
      uint32_t bits = gbits(kp0, kp1, fbase | (uint32_t)j);
      if (bi < 0 || bits > bb) { bb = bits; bi = j; }  // j ascending -> first max kept
    }
  }
  rb[tid] = bb; ri[tid] = bi; rc[tid] = cnt;
  __syncthreads();
  for (int s = 128; s > 0; s >>= 1) {
    if (tid < s) {
      int o = tid + s;
      int pi = ri[o];
      if (pi >= 0 && (ri[tid] < 0 || rb[o] > rb[tid] ||
                      (rb[o] == rb[tid] && pi < ri[tid]))) { rb[tid] = rb[o]; ri[tid] = pi; }
      rc[tid] += rc[o];
    }
    __syncthreads();
  }
  if (tid == 0) s_pidx = (rc[0] >= 2) ? ri[0] : 0;  // no positive -> argmax(-inf)=0
  __syncthreads();
  int pidx = s_pidx;
  if (tid < 128) red[tid] = emb[i * D + tid] * emb[pidx * D + tid];
  __syncthreads();
  for (int s = 64; s > 0; s >>= 1) {
    if (tid < s) red[tid] += red[tid + s];
    __syncthreads();
  }
  if (tid == 0) {
    float dot = red[0];
    float d2 = __fadd_rn(__fsub_rn(sq[pidx], __fmul_rn(2.0f, dot)), sq[i]);
    apod[i] = __fsqrt_rn(fmaxf(d2, 0.0f));
    posx[i] = pidx;
    validf[i] = (rc[0] >= 2 && rc[0] < B) ? 1 : 0;
  }
}

__global__ void init_kernel(float* accum) { accum[0] = 0.0f; accum[1] = 0.0f; }

// ---- 3. main scan: d[i,j] for all negatives; semi-hard gumbel-argmax + hardest fallback ----
// grid (128 anchor-tiles, 4 j-chunks), 256 threads, 64x64 tile, 4x4 per thread.
__global__ __launch_bounds__(256) void main_kernel(
    const float* __restrict__ emb, const int* __restrict__ labels,
    const float* __restrict__ sq, const float* __restrict__ ap,
    uint32_t kn0, uint32_t kn1,
    uint32_t* __restrict__ psb, int* __restrict__ psi,
    float* __restrict__ phd, int* __restrict__ phi) {
  __shared__ __align__(16) float sA[64][132];  // +4 pad: breaks power-of-2 row stride
  __shared__ __align__(16) float sB[64][132];
  __shared__ float s_sqj[64];
  __shared__ int s_labj[64];

  const int tid = threadIdx.x;
  const int tx = tid & 15, ty = tid >> 4;
  const int ia_base = blockIdx.x * 64;
  const int j0 = blockIdx.y * (B / 4);

  for (int idx = tid; idx < 64 * 32; idx += 256) {
    int r = idx >> 5, c = (idx & 31) << 2;
    *(float4*)&sA[r][c] = *(const float4*)&emb[(ia_base + r) * D + c];
  }

  float my_sq[4], my_ap[4], my_apm[4];
  int my_lab[4];
  #pragma unroll
  for (int aa = 0; aa < 4; aa++) {
    int ia = ia_base + ty * 4 + aa;
    my_sq[aa] = sq[ia];
    my_ap[aa] = ap[ia];
    my_apm[aa] = __fadd_rn(my_ap[aa], MARGIN);
    my_lab[aa] = labels[ia];
  }
  uint32_t sbits[4]; int sidx[4]; float hdv[4]; int hidx[4];
  #pragma unroll
  for (int aa = 0; aa < 4; aa++) { sbits[aa] = 0; sidx[aa] = -1; hdv[aa] = 3.0e38f; hidx[aa] = -1; }

  for (int jt = 0; jt < B / 4; jt += 64) {
    __syncthreads();
    for (int idx = tid; idx < 64 * 32; idx += 256) {
      int r = idx >> 5, c = (idx & 31) << 2;
      *(float4*)&sB[r][c] = *(const float4*)&emb[(j0 + jt + r) * D + c];
    }
    if (tid < 64) { s_sqj[tid] = sq[j0 + jt + tid]; s_labj[tid] = labels[j0 + jt + tid]; }
    __syncthreads();

    float acc[4][4];
    #pragma unroll
    for (int aa = 0; aa < 4; aa++)
      #pragma unroll
      for (int jj = 0; jj < 4; jj++) acc[aa][jj] = 0.0f;

    #pragma unroll 4
    for (int k = 0; k < D; k += 4) {
      float4 av[4], bv[4];
      #pragma unroll
      for (int aa = 0; aa < 4; aa++) av[aa] = *(const float4*)&sA[ty * 4 + aa][k];
      #pragma unroll
      for (int jj = 0; jj < 4; jj++) bv[jj] = *(const float4*)&sB[tx * 4 + jj][k];
      #pragma unroll
      for (int aa = 0; aa < 4; aa++)
        #pragma unroll
        for (int jj = 0; jj < 4; jj++) {
          acc[aa][jj] = fmaf(av[aa].x, bv[jj].x, acc[aa][jj]);
          acc[aa][jj] = fmaf(av[aa].y, bv[jj].y, acc[aa][jj]);
          acc[aa][jj] = fmaf(av[aa].z, bv[jj].z, acc[aa][jj]);
          acc[aa][jj] = fmaf(av[aa].w, bv[jj].w, acc[aa][jj]);
        }
    }

    // epilogue: per-entry mining updates (j ascending per anchor within thread)
    #pragma unroll
    for (int aa = 0; aa < 4; aa++) {
      int ia = ia_base + ty * 4 + aa;
      uint32_t fbase = (uint32_t)ia << 13;
      #pragma unroll
      for (int jj = 0; jj < 4; jj++) {
        int jl = tx * 4 + jj;
        int j = j0 + jt + jl;
        if (s_labj[jl] != my_lab[aa]) {
          float dot = acc[aa][jj];
          float d2 = __fadd_rn(__fsub_rn(s_sqj[jl], __fmul_rn(2.0f, dot)), my_sq[aa]);
          float d = __fsqrt_rn(fmaxf(d2, 0.0f));
          if (d < hdv[aa]) { hdv[aa] = d; hidx[aa] = j; }
          if (d > my_ap[aa] && d < my_apm[aa]) {
            uint32_t bits = gbits(kn0, kn1, fbase | (uint32_t)j);
            if (sidx[aa] < 0 || bits > sbits[aa]) { sbits[aa] = bits; sidx[aa] = j; }
          }
        }
      }
    }
  }

  // reduce 16 tx-threads per anchor via LDS (alias sA; compute is done)
  __syncthreads();
  uint32_t* r_sb = (uint32_t*)&sA[0][0];
  int* r_si = (int*)(r_sb + 1024);
  float* r_hd = (float*)(r_sb + 2048);
  int* r_hi = (int*)(r_sb + 3072);
  #pragma unroll
  for (int aa = 0; aa < 4; aa++) {
    int a = ty * 4 + aa;
    r_sb[a * 16 + tx] = sbits[aa];
    r_si[a * 16 + tx] = sidx[aa];
    r_hd[a * 16 + tx] = hdv[aa];
    r_hi[a * 16 + tx] = hidx[aa];
  }
  __syncthreads();
  if (tid < 64) {
    uint32_t sb = 0; int si = -1; float hd = 3.0e38f; int hi_ = -1;
    for (int t = 0; t < 16; t++) {
      int idx = tid * 16 + t;
      int pi = r_si[idx];
      if (pi >= 0) {
        uint32_t pb = r_sb[idx];
        if (si < 0 || pb > sb || (pb == sb && pi < si)) { sb = pb; si = pi; }
      }
      int ph = r_hi[idx];
      if (ph >= 0) {
        float pd = r_hd[idx];
        if (hi_ < 0 || pd < hd || (pd == hd && ph < hi_)) { hd = pd; hi_ = ph; }
      }
    }
    int out = (ia_base + tid) * 4 + blockIdx.y;
    psb[out] = sb; psi[out] = si; phd[out] = hd; phi[out] = hi_;
  }
}

// ---- 4. combine chunks + triplet loss (one wave per anchor) ----
__global__ __launch_bounds__(256) void finalize_kernel(
    const float* __restrict__ emb, const int* __restrict__ posx,
    const int* __restrict__ validf,
    const uint32_t* __restrict__ psb, const int* __restrict__ psi,
    const float* __restrict__ phd, const int* __restrict__ phi,
    float* __restrict__ accum) {
  int wid = threadIdx.x >> 6, lane = threadIdx.x & 63;
  int i = blockIdx.x * 4 + wid;

  uint32_t sb = 0; int si = -1; float hd = 3.0e38f; int hi_ = -1;
  #pragma unroll
  for (int c = 0; c < 4; c++) {
    int idx = i * 4 + c;
    int pi = psi[idx];
    if (pi >= 0) {
      uint32_t pb = psb[idx];
      if (si < 0 || pb > sb || (pb == sb && pi < si)) { sb = pb; si = pi; }
    }
    int ph = phi[idx];
    if (ph >= 0) {
      float pd = phd[idx];
      if (hi_ < 0 || pd < hd || (pd == hd && ph < hi_)) { hd = pd; hi_ = ph; }
    }
  }
  int neg = (si >= 0) ? si : ((hi_ >= 0) ? hi_ : 0);
  int pos = posx[i];

  float sap = 0.0f, san = 0.0f;
  #pragma unroll
  for (int k = lane; k < D; k += 64) {
    float a = emb[i * D + k];
    float dp = __fadd_rn(__fsub_rn(a, emb[pos * D + k]), EPS);
    float dn = __fadd_rn(__fsub_rn(a, emb[neg * D + k]), EPS);
    sap = fmaf(dp, dp, sap);
    san = fmaf(dn, dn, san);
  }
  #pragma unroll
  for (int off = 32; off > 0; off >>= 1) {
    sap += __shfl_down(sap, off);
    san += __shfl_down(san, off);
  }
  if (lane == 0 && validf[i]) {
    float per = __fadd_rn(__fsub_rn(__fsqrt_rn(sap), __fsqrt_rn(san)), MARGIN);
    per = fmaxf(per, 0.0f);
    atomicAdd(&accum[0], per);
    atomicAdd(&accum[1], 1.0f);
  }
}

__global__ void out_kernel(const float* __restrict__ accum, float* __restrict__ out) {
  out[0] = accum[0] / fmaxf(accum[1], 1.0f);
}

extern "C" void kernel_launch(void* const* d_in, const int* in_sizes, int n_in,
                              void* d_out, int out_size, void* d_ws, size_t ws_size,
                              hipStream_t stream) {
  const float* emb = (const float*)d_in[0];
  const int* labels = (const int*)d_in[1];
  char* ws = (char*)d_ws;
  float* sq      = (float*)(ws + 0);
  float* ap      = (float*)(ws + 32768);
  int* posx      = (int*)(ws + 65536);
  int* validf    = (int*)(ws + 98304);
  uint32_t* psb  = (uint32_t*)(ws + 131072);
  int* psi       = (int*)(ws + 262144);
  float* phd     = (float*)(ws + 393216);
  int* phi       = (int*)(ws + 524288);
  float* accum   = (float*)(ws + 655360);
  float* out     = (float*)d_out;

  // jax.random.key(42) -> split: threefry2x32((0,42), iota(4)) with
  // counter halves x0=[0,1], x1=[2,3]; kp=row0=(o0(0,2),o0(1,3)), kn=row1=(o1(0,2),o1(1,3))
  uint32_t A0, B0, A1, B1;
  tf2x32(0u, 42u, 0u, 2u, A0, B0);
  tf2x32(0u, 42u, 1u, 3u, A1, B1);
  uint32_t kp0 = A0, kp1 = A1, kn0 = B0, kn1 = B1;

  sq_kernel<<<B, 64, 0, stream>>>(emb, sq);
  pos_kernel<<<B, 256, 0, stream>>>(emb, labels, sq, kp0, kp1, posx, ap, validf);
  init_kernel<<<1, 1, 0, stream>>>(accum);
  main_kernel<<<dim3(B / 64, 4), 256, 0, stream>>>(emb, labels, sq, ap, kn0, kn1,
                                                   psb, psi, phd, phi);
  finalize_kernel<<<B / 4, 256, 0, stream>>>(emb, posx, validf, psb, psi, phd, phi, accum);
  out_kernel<<<1, 1, 0, stream>>>(accum, out);
}

// Round 2
// 478.077 us; speedup vs baseline: 1.7264x; 1.7264x over previous
//
#include <hip/hip_runtime.h>
#include <stdint.h>

#define B 8192
#define D 128
#define MARGIN 0.3f
#define EPS 1e-6f
#define HALFN (1u << 25)   // B*B/2 = 2^25
#define NCHUNK 16          // j-chunks for main kernel
#define JCH (B / NCHUNK)   // 512

using bf16x8 = __attribute__((ext_vector_type(8))) short;   // 8 bf16 = 4 VGPRs
using f32x16 = __attribute__((ext_vector_type(16))) float;  // MFMA 32x32 acc

// ---- Threefry-2x32 (JAX-compatible: 20 rounds, 5 key injections) ----
__host__ __device__ __forceinline__ void tf2x32(uint32_t k0, uint32_t k1,
                                                uint32_t x0, uint32_t x1,
                                                uint32_t& o0, uint32_t& o1) {
  uint32_t ks2 = k0 ^ k1 ^ 0x1BD11BDAu;
  uint32_t v0 = x0 + k0, v1 = x1 + k1;
#define RND(r) { v0 += v1; v1 = (v1 << (r)) | (v1 >> (32 - (r))); v1 ^= v0; }
  RND(13) RND(15) RND(26) RND(6)
  v0 += k1;  v1 += ks2 + 1u;
  RND(17) RND(29) RND(16) RND(24)
  v0 += ks2; v1 += k0 + 2u;
  RND(13) RND(15) RND(26) RND(6)
  v0 += k0;  v1 += k1 + 3u;
  RND(17) RND(29) RND(16) RND(24)
  v0 += k1;  v1 += ks2 + 4u;
  RND(13) RND(15) RND(26) RND(6)
  v0 += ks2; v1 += k0 + 5u;
#undef RND
  o0 = v0; o1 = v1;
}

// gumbel-argmax reduces to integer compare on (bits >> 9) -- strictly monotone.
__device__ __forceinline__ uint32_t gbits(uint32_t k0, uint32_t k1, uint32_t f) {
  bool lo = f < HALFN;
  uint32_t x0 = lo ? f : f - HALFN;
  uint32_t x1 = lo ? f + HALFN : f;
  uint32_t o0, o1;
  tf2x32(k0, k1, x0, x1, o0, o1);
  return (lo ? o0 : o1) >> 9;
}

__device__ __forceinline__ uint16_t f2bf(float f) {   // RNE float->bf16
  uint32_t u = __float_as_uint(f);
  return (uint16_t)((u + 0x7FFFu + ((u >> 16) & 1u)) >> 16);
}
__device__ __forceinline__ float bf2f(uint16_t b) {
  return __uint_as_float((uint32_t)b << 16);
}
__device__ __forceinline__ bf16x8 as_bf(uint4 u) {
  union { uint4 a; bf16x8 b; } x; x.a = u; return x.b;
}

// ---- 1. self dot products ----
__global__ void sq_kernel(const float* __restrict__ emb, float* __restrict__ sq) {
  int i = blockIdx.x, t = threadIdx.x;  // 64 threads
  float v0 = emb[i * D + t], v1 = emb[i * D + 64 + t];
  float s = v0 * v0 + v1 * v1;
  #pragma unroll
  for (int off = 32; off > 0; off >>= 1) s += __shfl_down(s, off);
  if (t == 0) sq[i] = s;
}

// ---- 2. split bf16 hi/lo into MFMA fragment-order chunk array ----
// chunk layout: [group g=row/32][kk=k/16][h=hi/lo][lane=(ksub<<5)|row%32] x 16B
__global__ __launch_bounds__(256) void prep_kernel(const float* __restrict__ emb,
                                                   uint32_t* __restrict__ chunk) {
  int tid = blockIdx.x * 256 + threadIdx.x;   // 131072 total
  int row = tid >> 4, oct = tid & 15;
  const float* src = emb + row * D + oct * 8;
  uint32_t hi[4], lo[4];
  #pragma unroll
  for (int e = 0; e < 4; e++) {
    float f0 = src[2 * e], f1 = src[2 * e + 1];
    uint16_t h0 = f2bf(f0), h1 = f2bf(f1);
    uint16_t l0 = f2bf(__fsub_rn(f0, bf2f(h0)));
    uint16_t l1 = f2bf(__fsub_rn(f1, bf2f(h1)));
    hi[e] = (uint32_t)h0 | ((uint32_t)h1 << 16);
    lo[e] = (uint32_t)l0 | ((uint32_t)l1 << 16);
  }
  int g = row >> 5, kk = oct >> 1, lane = ((oct & 1) << 5) | (row & 31);
  uint32_t base = ((g * 8 + kk) * 2) * 64 + lane;        // chunk index, h=0
  *(uint4*)&chunk[(size_t)base * 4]        = make_uint4(hi[0], hi[1], hi[2], hi[3]);
  *(uint4*)&chunk[(size_t)(base + 64) * 4] = make_uint4(lo[0], lo[1], lo[2], lo[3]);
}

// ---- 3. positive mining (exact fp32) ----
__global__ __launch_bounds__(256) void pos_kernel(
    const float* __restrict__ emb, const int* __restrict__ labels,
    const float* __restrict__ sq, uint32_t kp0, uint32_t kp1,
    int* __restrict__ posx, float* __restrict__ apod, int* __restrict__ validf) {
  __shared__ uint32_t rb[256];
  __shared__ int ri[256];
  __shared__ int rc[256];
  __shared__ float red[128];
  __shared__ int s_pidx;
  int i = blockIdx.x, tid = threadIdx.x;
  int lab = labels[i];
  uint32_t fbase = (uint32_t)i << 13;
  uint32_t bb = 0; int bi = -1; int cnt = 0;
  for (int j = tid; j < B; j += 256) {
    bool same = (labels[j] == lab);
    cnt += same ? 1 : 0;
    if (same && j != i) {
      uint32_t bits = gbits(kp0, kp1, fbase | (uint32_t)j);
      if (bi < 0 || bits > bb) { bb = bits; bi = j; }
    }
  }
  rb[tid] = bb; ri[tid] = bi; rc[tid] = cnt;
  __syncthreads();
  for (int s = 128; s > 0; s >>= 1) {
    if (tid < s) {
      int o = tid + s;
      int pi = ri[o];
      if (pi >= 0 && (ri[tid] < 0 || rb[o] > rb[tid] ||
                      (rb[o] == rb[tid] && pi < ri[tid]))) { rb[tid] = rb[o]; ri[tid] = pi; }
      rc[tid] += rc[o];
    }
    __syncthreads();
  }
  if (tid == 0) s_pidx = (rc[0] >= 2) ? ri[0] : 0;
  __syncthreads();
  int pidx = s_pidx;
  if (tid < 128) red[tid] = emb[i * D + tid] * emb[pidx * D + tid];
  __syncthreads();
  for (int s = 64; s > 0; s >>= 1) {
    if (tid < s) red[tid] += red[tid + s];
    __syncthreads();
  }
  if (tid == 0) {
    float dot = red[0];
    float d2 = __fadd_rn(__fsub_rn(sq[pidx], __fmul_rn(2.0f, dot)), sq[i]);
    apod[i] = __fsqrt_rn(fmaxf(d2, 0.0f));
    posx[i] = pidx;
    validf[i] = (rc[0] >= 2 && rc[0] < B) ? 1 : 0;
  }
}

__global__ void init_kernel(float* accum) { accum[0] = 0.0f; accum[1] = 0.0f; }

// ---- 4. main: split-bf16 MFMA GEMM + semi-hard mining ----
// grid (32 anchor-blocks, 16 j-chunks) x 256 thr. Block: 128 low + 128 high anchors
// (pairing i, i+4096 shares one threefry call). Wave w: M=2 tiles (low w, high w),
// A-frags full-K in 128 VGPRs; B tile (64 j, hi+lo) staged in LDS.
__global__ __launch_bounds__(256, 2) void main_kernel(
    const uint32_t* __restrict__ chunk, const int* __restrict__ labels,
    const float* __restrict__ sq, const float* __restrict__ ap,
    uint32_t kn0, uint32_t kn1,
    uint32_t* __restrict__ psb, int* __restrict__ psi,
    float* __restrict__ phd, int* __restrict__ phi) {
  __shared__ uint32_t ldsB[8192];   // 32 KB: [n0][kk][h][lane] 16B chunks
  __shared__ float scr[4352];       // 17 KB: per-wave 64 rows x 17 (stride 17 -> 2-way banks, free)
  __shared__ int s_labj[64];
  __shared__ float s_sqj[64];

  const int tid = threadIdx.x;
  const int w = tid >> 6, lane = tid & 63;
  const int p = lane & 31, khalf = lane >> 5;
  const int A0 = blockIdx.x * 128;
  const int jc = blockIdx.y;
  const int ia_lo = A0 + 32 * w + p;
  const int ia_up = ia_lo + 4096;
  float* myscr = &scr[w * 1088];

  // A fragments: 2 tiles x 8 ksteps x hi/lo = 32 x 16B = 128 VGPRs
  bf16x8 Af[2][8][2];
  {
    int g_lo = (A0 >> 5) + w;
    #pragma unroll
    for (int m = 0; m < 2; m++) {
      int g = g_lo + (m ? 128 : 0);
      #pragma unroll
      for (int kk = 0; kk < 8; kk++)
        #pragma unroll
        for (int h = 0; h < 2; h++)
          Af[m][kk][h] = as_bf(*(const uint4*)&chunk[(size_t)(((g * 8 + kk) * 2 + h) * 64 + lane) * 4]);
    }
  }

  const int lab_lo = labels[ia_lo], lab_up = labels[ia_up];
  const float sq_lo = sq[ia_lo], sq_up = sq[ia_up];
  const float ap_lo = ap[ia_lo], ap_up = ap[ia_up];
  const float apm_lo = __fadd_rn(ap_lo, MARGIN), apm_up = __fadd_rn(ap_up, MARGIN);
  uint32_t sb_lo = 0, sb_up = 0; int six_lo = -1, six_up = -1;
  float hd_lo = 3.0e38f, hd_up = 3.0e38f; int hix_lo = -1, hix_up = -1;

  for (int jt = 0; jt < JCH; jt += 64) {
    const int jb = jc * JCH + jt;
    __syncthreads();
    {
      const uint32_t* src = chunk + (size_t)(jb >> 5) * 4096;  // 2 groups = 8192 dwords
      #pragma unroll
      for (int q = 0; q < 8; q++) {
        int idx = tid + 256 * q;
        *(uint4*)&ldsB[idx * 4] = *(const uint4*)&src[idx * 4];
      }
      if (tid < 64) { s_labj[tid] = labels[jb + tid]; s_sqj[tid] = sq[jb + tid]; }
    }
    __syncthreads();

    f32x16 acc[2][2];
    #pragma unroll
    for (int m = 0; m < 2; m++)
      #pragma unroll
      for (int n = 0; n < 2; n++) acc[m][n] = (f32x16)(0.0f);

    #pragma unroll
    for (int kk = 0; kk < 8; kk++) {
      bf16x8 bh0 = *(const bf16x8*)&ldsB[(size_t)((0 * 16 + kk * 2 + 0) * 64 + lane) * 4];
      bf16x8 bl0 = *(const bf16x8*)&ldsB[(size_t)((0 * 16 + kk * 2 + 1) * 64 + lane) * 4];
      bf16x8 bh1 = *(const bf16x8*)&ldsB[(size_t)((1 * 16 + kk * 2 + 0) * 64 + lane) * 4];
      bf16x8 bl1 = *(const bf16x8*)&ldsB[(size_t)((1 * 16 + kk * 2 + 1) * 64 + lane) * 4];
      #pragma unroll
      for (int m = 0; m < 2; m++) {
        acc[m][0] = __builtin_amdgcn_mfma_f32_32x32x16_bf16(Af[m][kk][0], bh0, acc[m][0], 0, 0, 0);
        acc[m][0] = __builtin_amdgcn_mfma_f32_32x32x16_bf16(Af[m][kk][0], bl0, acc[m][0], 0, 0, 0);
        acc[m][0] = __builtin_amdgcn_mfma_f32_32x32x16_bf16(Af[m][kk][1], bh0, acc[m][0], 0, 0, 0);
        acc[m][1] = __builtin_amdgcn_mfma_f32_32x32x16_bf16(Af[m][kk][0], bh1, acc[m][1], 0, 0, 0);
        acc[m][1] = __builtin_amdgcn_mfma_f32_32x32x16_bf16(Af[m][kk][0], bl1, acc[m][1], 0, 0, 0);
        acc[m][1] = __builtin_amdgcn_mfma_f32_32x32x16_bf16(Af[m][kk][1], bh1, acc[m][1], 0, 0, 0);
      }
    }

    // mining epilogue: quarter-tiles of 16 cols through LDS scratch
    #pragma unroll
    for (int n0 = 0; n0 < 2; n0++) {
      #pragma unroll
      for (int qq = 0; qq < 2; qq++) {
        if (((lane >> 4) & 1) == qq) {
          #pragma unroll
          for (int m = 0; m < 2; m++)
            #pragma unroll
            for (int r = 0; r < 16; r++) {
              int row = (r & 3) + ((r >> 2) << 3) + (khalf << 2);  // C/D layout (m74/m101)
              myscr[(m * 32 + row) * 17 + (p & 15)] = acc[m][n0][r];
            }
        }
        __syncthreads();
        const int ch = khalf << 3;
        const uint32_t fb = (uint32_t)ia_lo << 13;
        for (int cc = 0; cc < 8; cc++) {
          int c16 = ch + cc;
          int jl = n0 * 32 + (qq << 4) + c16;
          int j = jb + jl;
          float dot_lo = myscr[p * 17 + c16];
          float dot_up = myscr[(32 + p) * 17 + c16];
          int lj = s_labj[jl]; float sj = s_sqj[jl];
          bool neg_lo = (lj != lab_lo), neg_up = (lj != lab_up);
          float d_lo = __fsqrt_rn(fmaxf(__fadd_rn(__fsub_rn(sj, __fmul_rn(2.0f, dot_lo)), sq_lo), 0.0f));
          float d_up = __fsqrt_rn(fmaxf(__fadd_rn(__fsub_rn(sj, __fmul_rn(2.0f, dot_up)), sq_up), 0.0f));
          if (neg_lo && d_lo < hd_lo) { hd_lo = d_lo; hix_lo = j; }
          if (neg_up && d_up < hd_up) { hd_up = d_up; hix_up = j; }
          bool in_lo = neg_lo && (d_lo > ap_lo) && (d_lo < apm_lo);
          bool in_up = neg_up && (d_up > ap_up) && (d_up < apm_up);
          if (in_lo || in_up) {
            uint32_t f = fb | (uint32_t)j;      // one threefry: o0->i, o1->i+4096
            uint32_t o0, o1;
            tf2x32(kn0, kn1, f, f + HALFN, o0, o1);
            uint32_t b_lo = o0 >> 9, b_up = o1 >> 9;
            if (in_lo && (six_lo < 0 || b_lo > sb_lo)) { sb_lo = b_lo; six_lo = j; }
            if (in_up && (six_up < 0 || b_up > sb_up)) { sb_up = b_up; six_up = j; }
          }
        }
        __syncthreads();
      }
    }
  }

  // merge col-halves (lane ^ 32), tie-break by smaller index
  {
    uint32_t ob; int oi; float od;
    ob = __shfl_xor(sb_lo, 32); oi = __shfl_xor(six_lo, 32);
    if (oi >= 0 && (six_lo < 0 || ob > sb_lo || (ob == sb_lo && oi < six_lo))) { sb_lo = ob; six_lo = oi; }
    ob = __shfl_xor(sb_up, 32); oi = __shfl_xor(six_up, 32);
    if (oi >= 0 && (six_up < 0 || ob > sb_up || (ob == sb_up && oi < six_up))) { sb_up = ob; six_up = oi; }
    od = __shfl_xor(hd_lo, 32); oi = __shfl_xor(hix_lo, 32);
    if (oi >= 0 && (hix_lo < 0 || od < hd_lo || (od == hd_lo && oi < hix_lo))) { hd_lo = od; hix_lo = oi; }
    od = __shfl_xor(hd_up, 32); oi = __shfl_xor(hix_up, 32);
    if (oi >= 0 && (hix_up < 0 || od < hd_up || (od == hd_up && oi < hix_up))) { hd_up = od; hix_up = oi; }
  }
  if (lane < 32) {
    int o = ia_lo * NCHUNK + jc;
    psb[o] = sb_lo; psi[o] = six_lo; phd[o] = hd_lo; phi[o] = hix_lo;
  } else {
    int o = ia_up * NCHUNK + jc;
    psb[o] = sb_up; psi[o] = six_up; phd[o] = hd_up; phi[o] = hix_up;
  }
}

// ---- 5. combine chunks + triplet loss ----
__global__ __launch_bounds__(256) void finalize_kernel(
    const float* __restrict__ emb, const int* __restrict__ posx,
    const int* __restrict__ validf,
    const uint32_t* __restrict__ psb, const int* __restrict__ psi,
    const float* __restrict__ phd, const int* __restrict__ phi,
    float* __restrict__ accum) {
  int wid = threadIdx.x >> 6, lane = threadIdx.x & 63;
  int i = blockIdx.x * 4 + wid;

  uint32_t sb = 0; int si = -1; float hd = 3.0e38f; int hi_ = -1;
  for (int c = 0; c < NCHUNK; c++) {
    int idx = i * NCHUNK + c;
    int pi = psi[idx];
    if (pi >= 0) {
      uint32_t pb = psb[idx];
      if (si < 0 || pb > sb || (pb == sb && pi < si)) { sb = pb; si = pi; }
    }
    int ph = phi[idx];
    if (ph >= 0) {
      float pd = phd[idx];
      if (hi_ < 0 || pd < hd || (pd == hd && ph < hi_)) { hd = pd; hi_ = ph; }
    }
  }
  int neg = (si >= 0) ? si : ((hi_ >= 0) ? hi_ : 0);
  int pos = posx[i];

  float sap = 0.0f, san = 0.0f;
  #pragma unroll
  for (int k = lane; k < D; k += 64) {
    float a = emb[i * D + k];
    float dp = __fadd_rn(__fsub_rn(a, emb[pos * D + k]), EPS);
    float dn = __fadd_rn(__fsub_rn(a, emb[neg * D + k]), EPS);
    sap = fmaf(dp, dp, sap);
    san = fmaf(dn, dn, san);
  }
  #pragma unroll
  for (int off = 32; off > 0; off >>= 1) {
    sap += __shfl_down(sap, off);
    san += __shfl_down(san, off);
  }
  if (lane == 0 && validf[i]) {
    float per = __fadd_rn(__fsub_rn(__fsqrt_rn(sap), __fsqrt_rn(san)), MARGIN);
    per = fmaxf(per, 0.0f);
    atomicAdd(&accum[0], per);
    atomicAdd(&accum[1], 1.0f);
  }
}

__global__ void out_kernel(const float* __restrict__ accum, float* __restrict__ out) {
  out[0] = accum[0] / fmaxf(accum[1], 1.0f);
}

extern "C" void kernel_launch(void* const* d_in, const int* in_sizes, int n_in,
                              void* d_out, int out_size, void* d_ws, size_t ws_size,
                              hipStream_t stream) {
  const float* emb = (const float*)d_in[0];
  const int* labels = (const int*)d_in[1];
  char* ws = (char*)d_ws;
  float* sq      = (float*)(ws + 0);          // 32 KB
  float* ap      = (float*)(ws + 32768);      // 32 KB
  int* posx      = (int*)(ws + 65536);        // 32 KB
  int* validf    = (int*)(ws + 98304);        // 32 KB
  float* accum   = (float*)(ws + 131072);     // 8 B
  uint32_t* psb  = (uint32_t*)(ws + 262144);  // 512 KB
  int* psi       = (int*)(ws + 786432);       // 512 KB
  float* phd     = (float*)(ws + 1310720);    // 512 KB
  int* phi       = (int*)(ws + 1835008);      // 512 KB
  uint32_t* chnk = (uint32_t*)(ws + 2359296); // 4 MB
  float* out     = (float*)d_out;

  // jax.random.key(42) -> split
  uint32_t A0, B0, A1, B1;
  tf2x32(0u, 42u, 0u, 2u, A0, B0);
  tf2x32(0u, 42u, 1u, 3u, A1, B1);
  uint32_t kp0 = A0, kp1 = A1, kn0 = B0, kn1 = B1;

  sq_kernel<<<B, 64, 0, stream>>>(emb, sq);
  prep_kernel<<<512, 256, 0, stream>>>(emb, chnk);
  pos_kernel<<<B, 256, 0, stream>>>(emb, labels, sq, kp0, kp1, posx, ap, validf);
  init_kernel<<<1, 1, 0, stream>>>(accum);
  main_kernel<<<dim3(32, NCHUNK), 256, 0, stream>>>(chnk, labels, sq, ap, kn0, kn1,
                                                    psb, psi, phd, phi);
  finalize_kernel<<<B / 4, 256, 0, stream>>>(emb, posx, validf, psb, psi, phd, phi, accum);
  out_kernel<<<1, 1, 0, stream>>>(accum, out);
}

// Round 3
// 275.595 us; speedup vs baseline: 2.9947x; 1.7347x over previous
//
#include <hip/hip_runtime.h>
#include <stdint.h>

#define B 8192
#define D 128
#define MARGIN 0.3f
#define EPS 1e-6f
#define HALFN (1u << 25)   // B*B/2 = 2^25
#define NCHUNK 16          // j-chunks for main kernel
#define JCH (B / NCHUNK)   // 512
#define NPART 2048         // finalize partial-sum blocks

using bf16x8 = __attribute__((ext_vector_type(8))) short;   // 8 bf16 = 4 VGPRs
using f32x16 = __attribute__((ext_vector_type(16))) float;  // MFMA 32x32 acc

// ---- Threefry-2x32 (JAX-compatible: 20 rounds, 5 key injections) ----
__host__ __device__ __forceinline__ void tf2x32(uint32_t k0, uint32_t k1,
                                                uint32_t x0, uint32_t x1,
                                                uint32_t& o0, uint32_t& o1) {
  uint32_t ks2 = k0 ^ k1 ^ 0x1BD11BDAu;
  uint32_t v0 = x0 + k0, v1 = x1 + k1;
#define RND(r) { v0 += v1; v1 = (v1 << (r)) | (v1 >> (32 - (r))); v1 ^= v0; }
  RND(13) RND(15) RND(26) RND(6)
  v0 += k1;  v1 += ks2 + 1u;
  RND(17) RND(29) RND(16) RND(24)
  v0 += ks2; v1 += k0 + 2u;
  RND(13) RND(15) RND(26) RND(6)
  v0 += k0;  v1 += k1 + 3u;
  RND(17) RND(29) RND(16) RND(24)
  v0 += k1;  v1 += ks2 + 4u;
  RND(13) RND(15) RND(26) RND(6)
  v0 += ks2; v1 += k0 + 5u;
#undef RND
  o0 = v0; o1 = v1;
}

// gumbel-argmax reduces to integer compare on (bits >> 9) -- strictly monotone.
__device__ __forceinline__ uint32_t gbits(uint32_t k0, uint32_t k1, uint32_t f) {
  bool lo = f < HALFN;
  uint32_t x0 = lo ? f : f - HALFN;
  uint32_t x1 = lo ? f + HALFN : f;
  uint32_t o0, o1;
  tf2x32(k0, k1, x0, x1, o0, o1);
  return (lo ? o0 : o1) >> 9;
}

__device__ __forceinline__ uint16_t f2bf(float f) {   // RNE float->bf16
  uint32_t u = __float_as_uint(f);
  return (uint16_t)((u + 0x7FFFu + ((u >> 16) & 1u)) >> 16);
}
__device__ __forceinline__ float bf2f(uint16_t b) {
  return __uint_as_float((uint32_t)b << 16);
}
__device__ __forceinline__ bf16x8 as_bf(uint4 u) {
  union { uint4 a; bf16x8 b; } x; x.a = u; return x.b;
}

// ---- 1. self dot products ----
__global__ void sq_kernel(const float* __restrict__ emb, float* __restrict__ sq) {
  int i = blockIdx.x, t = threadIdx.x;  // 64 threads
  float v0 = emb[i * D + t], v1 = emb[i * D + 64 + t];
  float s = v0 * v0 + v1 * v1;
  #pragma unroll
  for (int off = 32; off > 0; off >>= 1) s += __shfl_down(s, off);
  if (t == 0) sq[i] = s;
}

// ---- 2. split bf16 hi/lo into MFMA fragment-order chunk array ----
// chunk layout: [group g=row/32][kk=k/16][h=hi/lo][lane=(ksub<<5)|row%32] x 16B
__global__ __launch_bounds__(256) void prep_kernel(const float* __restrict__ emb,
                                                   uint32_t* __restrict__ chunk) {
  int tid = blockIdx.x * 256 + threadIdx.x;   // 131072 total
  int row = tid >> 4, oct = tid & 15;
  const float* src = emb + row * D + oct * 8;
  uint32_t hi[4], lo[4];
  #pragma unroll
  for (int e = 0; e < 4; e++) {
    float f0 = src[2 * e], f1 = src[2 * e + 1];
    uint16_t h0 = f2bf(f0), h1 = f2bf(f1);
    uint16_t l0 = f2bf(__fsub_rn(f0, bf2f(h0)));
    uint16_t l1 = f2bf(__fsub_rn(f1, bf2f(h1)));
    hi[e] = (uint32_t)h0 | ((uint32_t)h1 << 16);
    lo[e] = (uint32_t)l0 | ((uint32_t)l1 << 16);
  }
  int g = row >> 5, kk = oct >> 1, lane = ((oct & 1) << 5) | (row & 31);
  uint32_t base = ((g * 8 + kk) * 2) * 64 + lane;        // chunk index, h=0
  *(uint4*)&chunk[(size_t)base * 4]        = make_uint4(hi[0], hi[1], hi[2], hi[3]);
  *(uint4*)&chunk[(size_t)(base + 64) * 4] = make_uint4(lo[0], lo[1], lo[2], lo[3]);
}

// ---- 3. positive mining (exact fp32) ----
__global__ __launch_bounds__(256) void pos_kernel(
    const float* __restrict__ emb, const int* __restrict__ labels,
    const float* __restrict__ sq, uint32_t kp0, uint32_t kp1,
    int* __restrict__ posx, float* __restrict__ apod, int* __restrict__ validf) {
  __shared__ uint32_t rb[256];
  __shared__ int ri[256];
  __shared__ int rc[256];
  __shared__ float red[128];
  __shared__ int s_pidx;
  int i = blockIdx.x, tid = threadIdx.x;
  int lab = labels[i];
  uint32_t fbase = (uint32_t)i << 13;
  uint32_t bb = 0; int bi = -1; int cnt = 0;
  for (int j = tid; j < B; j += 256) {
    bool same = (labels[j] == lab);
    cnt += same ? 1 : 0;
    if (same && j != i) {
      uint32_t bits = gbits(kp0, kp1, fbase | (uint32_t)j);
      if (bi < 0 || bits > bb) { bb = bits; bi = j; }
    }
  }
  rb[tid] = bb; ri[tid] = bi; rc[tid] = cnt;
  __syncthreads();
  for (int s = 128; s > 0; s >>= 1) {
    if (tid < s) {
      int o = tid + s;
      int pi = ri[o];
      if (pi >= 0 && (ri[tid] < 0 || rb[o] > rb[tid] ||
                      (rb[o] == rb[tid] && pi < ri[tid]))) { rb[tid] = rb[o]; ri[tid] = pi; }
      rc[tid] += rc[o];
    }
    __syncthreads();
  }
  if (tid == 0) s_pidx = (rc[0] >= 2) ? ri[0] : 0;
  __syncthreads();
  int pidx = s_pidx;
  if (tid < 128) red[tid] = emb[i * D + tid] * emb[pidx * D + tid];
  __syncthreads();
  for (int s = 64; s > 0; s >>= 1) {
    if (tid < s) red[tid] += red[tid + s];
    __syncthreads();
  }
  if (tid == 0) {
    float dot = red[0];
    float d2 = __fadd_rn(__fsub_rn(sq[pidx], __fmul_rn(2.0f, dot)), sq[i]);
    apod[i] = __fsqrt_rn(fmaxf(d2, 0.0f));
    posx[i] = pidx;
    validf[i] = (rc[0] >= 2 && rc[0] < B) ? 1 : 0;
  }
}

// ---- 4. main: split-bf16 MFMA GEMM + semi-hard mining ----
// grid (32 anchor-blocks, 16 j-chunks) x 256 thr. Block: 128 low + 128 high anchors
// (pairing i, i+4096 shares one threefry call). Wave w: M=2 tiles (low w, high w),
// A-frags full-K in 128 VGPRs; B tile (64 j, hi+lo) staged in LDS.
__global__ __launch_bounds__(256, 2) void main_kernel(
    const uint32_t* __restrict__ chunk, const int* __restrict__ labels,
    const float* __restrict__ sq, const float* __restrict__ ap,
    uint32_t kn0, uint32_t kn1,
    uint32_t* __restrict__ psb, int* __restrict__ psi,
    float* __restrict__ phd, int* __restrict__ phi) {
  __shared__ uint32_t ldsB[8192];   // 32 KB: [n0][kk][h][lane] 16B chunks
  __shared__ float scr[4352];       // 17 KB: per-wave 64 rows x 17 (stride 17 -> 2-way banks, free)
  __shared__ int s_labj[64];
  __shared__ float s_sqj[64];

  const int tid = threadIdx.x;
  const int w = tid >> 6, lane = tid & 63;
  const int p = lane & 31, khalf = lane >> 5;
  const int A0 = blockIdx.x * 128;
  const int jc = blockIdx.y;
  const int ia_lo = A0 + 32 * w + p;
  const int ia_up = ia_lo + 4096;
  float* myscr = &scr[w * 1088];

  // A fragments: 2 tiles x 8 ksteps x hi/lo = 32 x 16B = 128 VGPRs
  bf16x8 Af[2][8][2];
  {
    int g_lo = (A0 >> 5) + w;
    #pragma unroll
    for (int m = 0; m < 2; m++) {
      int g = g_lo + (m ? 128 : 0);
      #pragma unroll
      for (int kk = 0; kk < 8; kk++)
        #pragma unroll
        for (int h = 0; h < 2; h++)
          Af[m][kk][h] = as_bf(*(const uint4*)&chunk[(size_t)(((g * 8 + kk) * 2 + h) * 64 + lane) * 4]);
    }
  }

  const int lab_lo = labels[ia_lo], lab_up = labels[ia_up];
  const float sq_lo = sq[ia_lo], sq_up = sq[ia_up];
  const float ap_lo = ap[ia_lo], ap_up = ap[ia_up];
  const float apm_lo = __fadd_rn(ap_lo, MARGIN), apm_up = __fadd_rn(ap_up, MARGIN);
  uint32_t sb_lo = 0, sb_up = 0; int six_lo = -1, six_up = -1;
  float hd_lo = 3.0e38f, hd_up = 3.0e38f; int hix_lo = -1, hix_up = -1;

  for (int jt = 0; jt < JCH; jt += 64) {
    const int jb = jc * JCH + jt;
    __syncthreads();
    {
      const uint32_t* src = chunk + (size_t)(jb >> 5) * 4096;  // 2 groups = 8192 dwords
      #pragma unroll
      for (int q = 0; q < 8; q++) {
        int idx = tid + 256 * q;
        *(uint4*)&ldsB[idx * 4] = *(const uint4*)&src[idx * 4];
      }
      if (tid < 64) { s_labj[tid] = labels[jb + tid]; s_sqj[tid] = sq[jb + tid]; }
    }
    __syncthreads();

    f32x16 acc[2][2];
    #pragma unroll
    for (int m = 0; m < 2; m++)
      #pragma unroll
      for (int n = 0; n < 2; n++) acc[m][n] = (f32x16)(0.0f);

    #pragma unroll
    for (int kk = 0; kk < 8; kk++) {
      bf16x8 bh0 = *(const bf16x8*)&ldsB[(size_t)((0 * 16 + kk * 2 + 0) * 64 + lane) * 4];
      bf16x8 bl0 = *(const bf16x8*)&ldsB[(size_t)((0 * 16 + kk * 2 + 1) * 64 + lane) * 4];
      bf16x8 bh1 = *(const bf16x8*)&ldsB[(size_t)((1 * 16 + kk * 2 + 0) * 64 + lane) * 4];
      bf16x8 bl1 = *(const bf16x8*)&ldsB[(size_t)((1 * 16 + kk * 2 + 1) * 64 + lane) * 4];
      #pragma unroll
      for (int m = 0; m < 2; m++) {
        acc[m][0] = __builtin_amdgcn_mfma_f32_32x32x16_bf16(Af[m][kk][0], bh0, acc[m][0], 0, 0, 0);
        acc[m][0] = __builtin_amdgcn_mfma_f32_32x32x16_bf16(Af[m][kk][0], bl0, acc[m][0], 0, 0, 0);
        acc[m][0] = __builtin_amdgcn_mfma_f32_32x32x16_bf16(Af[m][kk][1], bh0, acc[m][0], 0, 0, 0);
        acc[m][1] = __builtin_amdgcn_mfma_f32_32x32x16_bf16(Af[m][kk][0], bh1, acc[m][1], 0, 0, 0);
        acc[m][1] = __builtin_amdgcn_mfma_f32_32x32x16_bf16(Af[m][kk][0], bl1, acc[m][1], 0, 0, 0);
        acc[m][1] = __builtin_amdgcn_mfma_f32_32x32x16_bf16(Af[m][kk][1], bh1, acc[m][1], 0, 0, 0);
      }
    }

    // mining epilogue: quarter-tiles of 16 cols through LDS scratch
    #pragma unroll
    for (int n0 = 0; n0 < 2; n0++) {
      #pragma unroll
      for (int qq = 0; qq < 2; qq++) {
        if (((lane >> 4) & 1) == qq) {
          #pragma unroll
          for (int m = 0; m < 2; m++)
            #pragma unroll
            for (int r = 0; r < 16; r++) {
              int row = (r & 3) + ((r >> 2) << 3) + (khalf << 2);  // C/D layout (m74/m101)
              myscr[(m * 32 + row) * 17 + (p & 15)] = acc[m][n0][r];
            }
        }
        __syncthreads();
        const int ch = khalf << 3;
        const uint32_t fb = (uint32_t)ia_lo << 13;
        for (int cc = 0; cc < 8; cc++) {
          int c16 = ch + cc;
          int jl = n0 * 32 + (qq << 4) + c16;
          int j = jb + jl;
          float dot_lo = myscr[p * 17 + c16];
          float dot_up = myscr[(32 + p) * 17 + c16];
          int lj = s_labj[jl]; float sj = s_sqj[jl];
          bool neg_lo = (lj != lab_lo), neg_up = (lj != lab_up);
          float d_lo = __fsqrt_rn(fmaxf(__fadd_rn(__fsub_rn(sj, __fmul_rn(2.0f, dot_lo)), sq_lo), 0.0f));
          float d_up = __fsqrt_rn(fmaxf(__fadd_rn(__fsub_rn(sj, __fmul_rn(2.0f, dot_up)), sq_up), 0.0f));
          if (neg_lo && d_lo < hd_lo) { hd_lo = d_lo; hix_lo = j; }
          if (neg_up && d_up < hd_up) { hd_up = d_up; hix_up = j; }
          bool in_lo = neg_lo && (d_lo > ap_lo) && (d_lo < apm_lo);
          bool in_up = neg_up && (d_up > ap_up) && (d_up < apm_up);
          if (in_lo || in_up) {
            uint32_t f = fb | (uint32_t)j;      // one threefry: o0->i, o1->i+4096
            uint32_t o0, o1;
            tf2x32(kn0, kn1, f, f + HALFN, o0, o1);
            uint32_t b_lo = o0 >> 9, b_up = o1 >> 9;
            if (in_lo && (six_lo < 0 || b_lo > sb_lo)) { sb_lo = b_lo; six_lo = j; }
            if (in_up && (six_up < 0 || b_up > sb_up)) { sb_up = b_up; six_up = j; }
          }
        }
        __syncthreads();
      }
    }
  }

  // merge col-halves (lane ^ 32), tie-break by smaller index
  {
    uint32_t ob; int oi; float od;
    ob = __shfl_xor(sb_lo, 32); oi = __shfl_xor(six_lo, 32);
    if (oi >= 0 && (six_lo < 0 || ob > sb_lo || (ob == sb_lo && oi < six_lo))) { sb_lo = ob; six_lo = oi; }
    ob = __shfl_xor(sb_up, 32); oi = __shfl_xor(six_up, 32);
    if (oi >= 0 && (six_up < 0 || ob > sb_up || (ob == sb_up && oi < six_up))) { sb_up = ob; six_up = oi; }
    od = __shfl_xor(hd_lo, 32); oi = __shfl_xor(hix_lo, 32);
    if (oi >= 0 && (hix_lo < 0 || od < hd_lo || (od == hd_lo && oi < hix_lo))) { hd_lo = od; hix_lo = oi; }
    od = __shfl_xor(hd_up, 32); oi = __shfl_xor(hix_up, 32);
    if (oi >= 0 && (hix_up < 0 || od < hd_up || (od == hd_up && oi < hix_up))) { hd_up = od; hix_up = oi; }
  }
  if (lane < 32) {
    int o = ia_lo * NCHUNK + jc;
    psb[o] = sb_lo; psi[o] = six_lo; phd[o] = hd_lo; phi[o] = hix_lo;
  } else {
    int o = ia_up * NCHUNK + jc;
    psb[o] = sb_up; psi[o] = six_up; phd[o] = hd_up; phi[o] = hix_up;
  }
}

// ---- 5. combine chunks + triplet loss -> per-block partials (NO atomics) ----
__global__ __launch_bounds__(256) void finalize_kernel(
    const float* __restrict__ emb, const int* __restrict__ posx,
    const int* __restrict__ validf,
    const uint32_t* __restrict__ psb, const int* __restrict__ psi,
    const float* __restrict__ phd, const int* __restrict__ phi,
    float* __restrict__ pers, float* __restrict__ cnts) {
  __shared__ float s_per[4];
  __shared__ float s_cnt[4];
  int wid = threadIdx.x >> 6, lane = threadIdx.x & 63;
  int i = blockIdx.x * 4 + wid;

  uint32_t sb = 0; int si = -1; float hd = 3.0e38f; int hi_ = -1;
  for (int c = 0; c < NCHUNK; c++) {
    int idx = i * NCHUNK + c;
    int pi = psi[idx];
    if (pi >= 0) {
      uint32_t pb = psb[idx];
      if (si < 0 || pb > sb || (pb == sb && pi < si)) { sb = pb; si = pi; }
    }
    int ph = phi[idx];
    if (ph >= 0) {
      float pd = phd[idx];
      if (hi_ < 0 || pd < hd || (pd == hd && ph < hi_)) { hd = pd; hi_ = ph; }
    }
  }
  int neg = (si >= 0) ? si : ((hi_ >= 0) ? hi_ : 0);
  int pos = posx[i];

  float sap = 0.0f, san = 0.0f;
  #pragma unroll
  for (int k = lane; k < D; k += 64) {
    float a = emb[i * D + k];
    float dp = __fadd_rn(__fsub_rn(a, emb[pos * D + k]), EPS);
    float dn = __fadd_rn(__fsub_rn(a, emb[neg * D + k]), EPS);
    sap = fmaf(dp, dp, sap);
    san = fmaf(dn, dn, san);
  }
  #pragma unroll
  for (int off = 32; off > 0; off >>= 1) {
    sap += __shfl_down(sap, off);
    san += __shfl_down(san, off);
  }
  if (lane == 0) {
    int v = validf[i];
    float per = __fadd_rn(__fsub_rn(__fsqrt_rn(sap), __fsqrt_rn(san)), MARGIN);
    per = fmaxf(per, 0.0f);
    s_per[wid] = v ? per : 0.0f;
    s_cnt[wid] = v ? 1.0f : 0.0f;
  }
  __syncthreads();
  if (threadIdx.x == 0) {
    pers[blockIdx.x] = s_per[0] + s_per[1] + s_per[2] + s_per[3];
    cnts[blockIdx.x] = s_cnt[0] + s_cnt[1] + s_cnt[2] + s_cnt[3];
  }
}

// ---- 6. reduce partials -> final loss ----
__global__ __launch_bounds__(256) void reduce_kernel(
    const float* __restrict__ pers, const float* __restrict__ cnts,
    float* __restrict__ out) {
  __shared__ float rp[256], rcn[256];
  int tid = threadIdx.x;
  float sp = 0.0f, sc = 0.0f;
  #pragma unroll
  for (int q = 0; q < NPART / 256; q++) {
    sp += pers[tid + 256 * q];
    sc += cnts[tid + 256 * q];
  }
  rp[tid] = sp; rcn[tid] = sc;
  __syncthreads();
  for (int s = 128; s > 0; s >>= 1) {
    if (tid < s) { rp[tid] += rp[tid + s]; rcn[tid] += rcn[tid + s]; }
    __syncthreads();
  }
  if (tid == 0) out[0] = rp[0] / fmaxf(rcn[0], 1.0f);
}

extern "C" void kernel_launch(void* const* d_in, const int* in_sizes, int n_in,
                              void* d_out, int out_size, void* d_ws, size_t ws_size,
                              hipStream_t stream) {
  const float* emb = (const float*)d_in[0];
  const int* labels = (const int*)d_in[1];
  char* ws = (char*)d_ws;
  float* sq      = (float*)(ws + 0);          // 32 KB
  float* ap      = (float*)(ws + 32768);      // 32 KB
  int* posx      = (int*)(ws + 65536);        // 32 KB
  int* validf    = (int*)(ws + 98304);        // 32 KB
  float* pers    = (float*)(ws + 131072);     // 8 KB
  float* cnts    = (float*)(ws + 147456);     // 8 KB
  uint32_t* psb  = (uint32_t*)(ws + 262144);  // 512 KB
  int* psi       = (int*)(ws + 786432);       // 512 KB
  float* phd     = (float*)(ws + 1310720);    // 512 KB
  int* phi       = (int*)(ws + 1835008);      // 512 KB
  uint32_t* chnk = (uint32_t*)(ws + 2359296); // 4 MB
  float* out     = (float*)d_out;

  // jax.random.key(42) -> split
  uint32_t A0, B0, A1, B1;
  tf2x32(0u, 42u, 0u, 2u, A0, B0);
  tf2x32(0u, 42u, 1u, 3u, A1, B1);
  uint32_t kp0 = A0, kp1 = A1, kn0 = B0, kn1 = B1;

  sq_kernel<<<B, 64, 0, stream>>>(emb, sq);
  prep_kernel<<<512, 256, 0, stream>>>(emb, chnk);
  pos_kernel<<<B, 256, 0, stream>>>(emb, labels, sq, kp0, kp1, posx, ap, validf);
  main_kernel<<<dim3(32, NCHUNK), 256, 0, stream>>>(chnk, labels, sq, ap, kn0, kn1,
                                                    psb, psi, phd, phi);
  finalize_kernel<<<NPART, 256, 0, stream>>>(emb, posx, validf, psb, psi, phd, phi,
                                             pers, cnts);
  reduce_kernel<<<1, 256, 0, stream>>>(pers, cnts, out);
}

// Round 4
// 243.958 us; speedup vs baseline: 3.3831x; 1.1297x over previous
//
#include <hip/hip_runtime.h>
#include <stdint.h>

#define B 8192
#define D 128
#define MARGIN 0.3f
#define EPS 1e-6f
#define HALFN (1u << 25)   // B*B/2 = 2^25
#define NCHUNK 16          // j-chunks for main kernel
#define JCH (B / NCHUNK)   // 512
#define NPART 2048         // finalize partial-sum blocks

using bf16x8 = __attribute__((ext_vector_type(8))) short;   // 8 bf16 = 4 VGPRs
using f32x16 = __attribute__((ext_vector_type(16))) float;  // MFMA 32x32 acc

// ---- Threefry-2x32 (JAX-compatible: 20 rounds, 5 key injections) ----
__host__ __device__ __forceinline__ void tf2x32(uint32_t k0, uint32_t k1,
                                                uint32_t x0, uint32_t x1,
                                                uint32_t& o0, uint32_t& o1) {
  uint32_t ks2 = k0 ^ k1 ^ 0x1BD11BDAu;
  uint32_t v0 = x0 + k0, v1 = x1 + k1;
#define RND(r) { v0 += v1; v1 = (v1 << (r)) | (v1 >> (32 - (r))); v1 ^= v0; }
  RND(13) RND(15) RND(26) RND(6)
  v0 += k1;  v1 += ks2 + 1u;
  RND(17) RND(29) RND(16) RND(24)
  v0 += ks2; v1 += k0 + 2u;
  RND(13) RND(15) RND(26) RND(6)
  v0 += k0;  v1 += k1 + 3u;
  RND(17) RND(29) RND(16) RND(24)
  v0 += k1;  v1 += ks2 + 4u;
  RND(13) RND(15) RND(26) RND(6)
  v0 += ks2; v1 += k0 + 5u;
#undef RND
  o0 = v0; o1 = v1;
}

// gumbel-argmax reduces to integer compare on (bits >> 9) -- strictly monotone.
__device__ __forceinline__ uint32_t gbits(uint32_t k0, uint32_t k1, uint32_t f) {
  bool lo = f < HALFN;
  uint32_t x0 = lo ? f : f - HALFN;
  uint32_t x1 = lo ? f + HALFN : f;
  uint32_t o0, o1;
  tf2x32(k0, k1, x0, x1, o0, o1);
  return (lo ? o0 : o1) >> 9;
}

__device__ __forceinline__ uint16_t f2bf(float f) {   // RNE float->bf16
  uint32_t u = __float_as_uint(f);
  return (uint16_t)((u + 0x7FFFu + ((u >> 16) & 1u)) >> 16);
}
__device__ __forceinline__ float bf2f(uint16_t b) {
  return __uint_as_float((uint32_t)b << 16);
}
__device__ __forceinline__ bf16x8 as_bf(uint4 u) {
  union { uint4 a; bf16x8 b; } x; x.a = u; return x.b;
}

// ---- 1. split bf16 hi/lo into MFMA fragment-order chunk array + fused row norms ----
// chunk layout: [group g=row/32][kk=k/16][h=hi/lo][lane=(ksub<<5)|row%32] x 16B
__global__ __launch_bounds__(256) void prep_kernel(const float* __restrict__ emb,
                                                   uint32_t* __restrict__ chunk,
                                                   float* __restrict__ sq) {
  int tid = blockIdx.x * 256 + threadIdx.x;   // 131072 total
  int row = tid >> 4, oct = tid & 15;
  const float* src = emb + row * D + oct * 8;
  uint32_t hi[4], lo[4];
  float s = 0.0f;
  #pragma unroll
  for (int e = 0; e < 4; e++) {
    float f0 = src[2 * e], f1 = src[2 * e + 1];
    s = fmaf(f0, f0, s); s = fmaf(f1, f1, s);
    uint16_t h0 = f2bf(f0), h1 = f2bf(f1);
    uint16_t l0 = f2bf(__fsub_rn(f0, bf2f(h0)));
    uint16_t l1 = f2bf(__fsub_rn(f1, bf2f(h1)));
    hi[e] = (uint32_t)h0 | ((uint32_t)h1 << 16);
    lo[e] = (uint32_t)l0 | ((uint32_t)l1 << 16);
  }
  // row-sum over the 16 threads sharing this row (xor masks stay in-group)
  s += __shfl_xor(s, 1); s += __shfl_xor(s, 2);
  s += __shfl_xor(s, 4); s += __shfl_xor(s, 8);
  if (oct == 0) sq[row] = s;
  int g = row >> 5, kk = oct >> 1, lane = ((oct & 1) << 5) | (row & 31);
  uint32_t base = ((g * 8 + kk) * 2) * 64 + lane;        // chunk index, h=0
  *(uint4*)&chunk[(size_t)base * 4]        = make_uint4(hi[0], hi[1], hi[2], hi[3]);
  *(uint4*)&chunk[(size_t)(base + 64) * 4] = make_uint4(lo[0], lo[1], lo[2], lo[3]);
}

// ---- 2. positive mining (exact fp32); outputs squared band thresholds ----
__global__ __launch_bounds__(256) void pos_kernel(
    const float* __restrict__ emb, const int* __restrict__ labels,
    const float* __restrict__ sq, uint32_t kp0, uint32_t kp1,
    int* __restrict__ posx, float* __restrict__ ap2lo, float* __restrict__ ap2hi,
    int* __restrict__ validf) {
  __shared__ uint32_t rb[256];
  __shared__ int ri[256];
  __shared__ int rc[256];
  __shared__ float red[128];
  __shared__ int s_pidx;
  int i = blockIdx.x, tid = threadIdx.x;
  int lab = labels[i];
  uint32_t fbase = (uint32_t)i << 13;
  uint32_t bb = 0; int bi = -1; int cnt = 0;
  for (int j = tid; j < B; j += 256) {
    bool same = (labels[j] == lab);
    cnt += same ? 1 : 0;
    if (same && j != i) {
      uint32_t bits = gbits(kp0, kp1, fbase | (uint32_t)j);
      if (bi < 0 || bits > bb) { bb = bits; bi = j; }
    }
  }
  rb[tid] = bb; ri[tid] = bi; rc[tid] = cnt;
  __syncthreads();
  for (int s = 128; s > 0; s >>= 1) {
    if (tid < s) {
      int o = tid + s;
      int pi = ri[o];
      if (pi >= 0 && (ri[tid] < 0 || rb[o] > rb[tid] ||
                      (rb[o] == rb[tid] && pi < ri[tid]))) { rb[tid] = rb[o]; ri[tid] = pi; }
      rc[tid] += rc[o];
    }
    __syncthreads();
  }
  if (tid == 0) s_pidx = (rc[0] >= 2) ? ri[0] : 0;
  __syncthreads();
  int pidx = s_pidx;
  if (tid < 128) red[tid] = emb[i * D + tid] * emb[pidx * D + tid];
  __syncthreads();
  for (int s = 64; s > 0; s >>= 1) {
    if (tid < s) red[tid] += red[tid + s];
    __syncthreads();
  }
  if (tid == 0) {
    float dot = red[0];
    float d2 = __fadd_rn(__fsub_rn(sq[pidx], __fmul_rn(2.0f, dot)), sq[i]);
    float apv = __fsqrt_rn(fmaxf(d2, 0.0f));          // reference's rounded ap
    float apm = __fadd_rn(apv, MARGIN);
    ap2lo[i] = __fmul_rn(apv, apv);                   // band test moves to d^2 domain
    ap2hi[i] = __fmul_rn(apm, apm);
    posx[i] = pidx;
    validf[i] = (rc[0] >= 2 && rc[0] < B) ? 1 : 0;
  }
}

// ---- 3. main: swapped-operand MFMA (C[j][anchor]) + register-local mining ----
// grid (32 anchor-blocks, 16 j-chunks) x 256 thr. Wave w, lane: col p = lane&31
// = anchor pair (A0+32w+p, +4096). Anchors = B-operand (bf16-hi only, registers);
// j rows = A-operand (hi+lo, LDS). dot = (jh+jl)*ah -> 2 MFMAs per k-step.
__global__ __launch_bounds__(256, 2) void main_kernel(
    const uint32_t* __restrict__ chunk, const int* __restrict__ labels,
    const float* __restrict__ sq, const float* __restrict__ ap2lo,
    const float* __restrict__ ap2hi, uint32_t kn0, uint32_t kn1,
    uint32_t* __restrict__ psb, int* __restrict__ psi,
    float* __restrict__ phd2, int* __restrict__ phi) {
  __shared__ uint32_t ldsB[8192];   // 32 KB: [n0][kk][h][lane] 16B chunks (j rows)
  __shared__ int s_labj[64];
  __shared__ float s_sqj[64];

  const int tid = threadIdx.x;
  const int w = tid >> 6, lane = tid & 63;
  const int p = lane & 31, khalf = lane >> 5;
  const int A0 = blockIdx.x * 128;
  const int jc = blockIdx.y;
  const int ia_lo = A0 + 32 * w + p;
  const int ia_up = ia_lo + 4096;

  // anchor B-frags (hi only): 2 tiles x 8 ksteps = 16 x 16B = 64 VGPRs
  bf16x8 Af[2][8];
  {
    int g_lo = (A0 >> 5) + w;
    #pragma unroll
    for (int m = 0; m < 2; m++) {
      int g = g_lo + (m ? 128 : 0);
      #pragma unroll
      for (int kk = 0; kk < 8; kk++)
        Af[m][kk] = as_bf(*(const uint4*)&chunk[(size_t)(((g * 8 + kk) * 2) * 64 + lane) * 4]);
    }
  }

  const int lab_lo = labels[ia_lo], lab_up = labels[ia_up];
  const float sq_lo = sq[ia_lo], sq_up = sq[ia_up];
  const float tl2_lo = ap2lo[ia_lo], tl2_up = ap2lo[ia_up];
  const float th2_lo = ap2hi[ia_lo], th2_up = ap2hi[ia_up];
  const uint32_t fb = (uint32_t)ia_lo << 13;
  uint32_t sb_lo = 0, sb_up = 0; int six_lo = -1, six_up = -1;
  float hd_lo = 3.0e38f, hd_up = 3.0e38f; int hix_lo = -1, hix_up = -1;

  for (int jt = 0; jt < JCH; jt += 64) {
    const int jb = jc * JCH + jt;
    __syncthreads();
    {
      const uint32_t* src = chunk + (size_t)(jb >> 5) * 4096;  // 2 groups = 8192 dwords
      #pragma unroll
      for (int q = 0; q < 8; q++) {
        int idx = tid + 256 * q;
        *(uint4*)&ldsB[idx * 4] = *(const uint4*)&src[idx * 4];
      }
      if (tid < 64) { s_labj[tid] = labels[jb + tid]; s_sqj[tid] = sq[jb + tid]; }
    }
    __syncthreads();

    f32x16 acc[2][2];   // [n0 = j-subtile][m = anchor tile lo/up]
    #pragma unroll
    for (int n = 0; n < 2; n++)
      #pragma unroll
      for (int m = 0; m < 2; m++) acc[n][m] = (f32x16)(0.0f);

    #pragma unroll
    for (int kk = 0; kk < 8; kk++) {
      bf16x8 jh0 = *(const bf16x8*)&ldsB[(size_t)((0 * 16 + kk * 2 + 0) * 64 + lane) * 4];
      bf16x8 jl0 = *(const bf16x8*)&ldsB[(size_t)((0 * 16 + kk * 2 + 1) * 64 + lane) * 4];
      bf16x8 jh1 = *(const bf16x8*)&ldsB[(size_t)((1 * 16 + kk * 2 + 0) * 64 + lane) * 4];
      bf16x8 jl1 = *(const bf16x8*)&ldsB[(size_t)((1 * 16 + kk * 2 + 1) * 64 + lane) * 4];
      #pragma unroll
      for (int m = 0; m < 2; m++) {
        acc[0][m] = __builtin_amdgcn_mfma_f32_32x32x16_bf16(jh0, Af[m][kk], acc[0][m], 0, 0, 0);
        acc[0][m] = __builtin_amdgcn_mfma_f32_32x32x16_bf16(jl0, Af[m][kk], acc[0][m], 0, 0, 0);
        acc[1][m] = __builtin_amdgcn_mfma_f32_32x32x16_bf16(jh1, Af[m][kk], acc[1][m], 0, 0, 0);
        acc[1][m] = __builtin_amdgcn_mfma_f32_32x32x16_bf16(jl1, Af[m][kk], acc[1][m], 0, 0, 0);
      }
    }

    // mining epilogue: register-local per lane (col = anchor), j ascending;
    // threefry unconditional -> 32 independent chains for the scheduler.
    #pragma unroll
    for (int n0 = 0; n0 < 2; n0++) {
      #pragma unroll
      for (int r = 0; r < 16; r++) {
        int row = (r & 3) + ((r >> 2) << 3) + (khalf << 2);  // C/D row map (m74/m101)
        int jl = n0 * 32 + row;
        int j = jb + jl;
        float sj = s_sqj[jl];        // wave-uniform per khalf -> LDS broadcast
        int lj = s_labj[jl];
        float d2lo = __fadd_rn(fmaf(-2.0f, acc[n0][0][r], sj), sq_lo);
        float d2up = __fadd_rn(fmaf(-2.0f, acc[n0][1][r], sj), sq_up);
        bool neg_lo = (lj != lab_lo), neg_up = (lj != lab_up);
        if (neg_lo && d2lo < hd_lo) { hd_lo = d2lo; hix_lo = j; }
        if (neg_up && d2up < hd_up) { hd_up = d2up; hix_up = j; }
        uint32_t f = fb | (uint32_t)j, o0, o1;
        tf2x32(kn0, kn1, f, f + HALFN, o0, o1);   // o0 -> i, o1 -> i+4096
        uint32_t b_lo = o0 >> 9, b_up = o1 >> 9;
        bool in_lo = neg_lo && (d2lo > tl2_lo) && (d2lo < th2_lo);
        bool in_up = neg_up && (d2up > tl2_up) && (d2up < th2_up);
        if (in_lo && (six_lo < 0 || b_lo > sb_lo)) { sb_lo = b_lo; six_lo = j; }
        if (in_up && (six_up < 0 || b_up > sb_up)) { sb_up = b_up; six_up = j; }
      }
    }
  }

  // merge row-halves (lane ^ 32 holds same anchors, other 16 j-rows per subtile)
  {
    uint32_t ob; int oi; float od;
    ob = __shfl_xor(sb_lo, 32); oi = __shfl_xor(six_lo, 32);
    if (oi >= 0 && (six_lo < 0 || ob > sb_lo || (ob == sb_lo && oi < six_lo))) { sb_lo = ob; six_lo = oi; }
    ob = __shfl_xor(sb_up, 32); oi = __shfl_xor(six_up, 32);
    if (oi >= 0 && (six_up < 0 || ob > sb_up || (ob == sb_up && oi < six_up))) { sb_up = ob; six_up = oi; }
    od = __shfl_xor(hd_lo, 32); oi = __shfl_xor(hix_lo, 32);
    if (oi >= 0 && (hix_lo < 0 || od < hd_lo || (od == hd_lo && oi < hix_lo))) { hd_lo = od; hix_lo = oi; }
    od = __shfl_xor(hd_up, 32); oi = __shfl_xor(hix_up, 32);
    if (oi >= 0 && (hix_up < 0 || od < hd_up || (od == hd_up && oi < hix_up))) { hd_up = od; hix_up = oi; }
  }
  if (lane < 32) {
    int o = ia_lo * NCHUNK + jc;
    psb[o] = sb_lo; psi[o] = six_lo; phd2[o] = hd_lo; phi[o] = hix_lo;
  } else {
    int o = ia_up * NCHUNK + jc;
    psb[o] = sb_up; psi[o] = six_up; phd2[o] = hd_up; phi[o] = hix_up;
  }
}

// ---- 4. combine chunks + triplet loss -> per-block partials (no atomics) ----
__global__ __launch_bounds__(256) void finalize_kernel(
    const float* __restrict__ emb, const int* __restrict__ posx,
    const int* __restrict__ validf,
    const uint32_t* __restrict__ psb, const int* __restrict__ psi,
    const float* __restrict__ phd2, const int* __restrict__ phi,
    float* __restrict__ pers, float* __restrict__ cnts) {
  __shared__ float s_per[4];
  __shared__ float s_cnt[4];
  int wid = threadIdx.x >> 6, lane = threadIdx.x & 63;
  int i = blockIdx.x * 4 + wid;

  uint32_t sb = 0; int si = -1; float hd = 3.0e38f; int hi_ = -1;
  for (int c = 0; c < NCHUNK; c++) {
    int idx = i * NCHUNK + c;
    int pi = psi[idx];
    if (pi >= 0) {
      uint32_t pb = psb[idx];
      if (si < 0 || pb > sb || (pb == sb && pi < si)) { sb = pb; si = pi; }
    }
    int ph = phi[idx];
    if (ph >= 0) {
      float pd = phd2[idx];
      if (hi_ < 0 || pd < hd || (pd == hd && ph < hi_)) { hd = pd; hi_ = ph; }
    }
  }
  int neg = (si >= 0) ? si : ((hi_ >= 0) ? hi_ : 0);
  int pos = posx[i];

  float sap = 0.0f, san = 0.0f;
  #pragma unroll
  for (int k = lane; k < D; k += 64) {
    float a = emb[i * D + k];
    float dp = __fadd_rn(__fsub_rn(a, emb[pos * D + k]), EPS);
    float dn = __fadd_rn(__fsub_rn(a, emb[neg * D + k]), EPS);
    sap = fmaf(dp, dp, sap);
    san = fmaf(dn, dn, san);
  }
  #pragma unroll
  for (int off = 32; off > 0; off >>= 1) {
    sap += __shfl_down(sap, off);
    san += __shfl_down(san, off);
  }
  if (lane == 0) {
    int v = validf[i];
    float per = __fadd_rn(__fsub_rn(__fsqrt_rn(sap), __fsqrt_rn(san)), MARGIN);
    per = fmaxf(per, 0.0f);
    s_per[wid] = v ? per : 0.0f;
    s_cnt[wid] = v ? 1.0f : 0.0f;
  }
  __syncthreads();
  if (threadIdx.x == 0) {
    pers[blockIdx.x] = s_per[0] + s_per[1] + s_per[2] + s_per[3];
    cnts[blockIdx.x] = s_cnt[0] + s_cnt[1] + s_cnt[2] + s_cnt[3];
  }
}

// ---- 5. reduce partials -> final loss ----
__global__ __launch_bounds__(256) void reduce_kernel(
    const float* __restrict__ pers, const float* __restrict__ cnts,
    float* __restrict__ out) {
  __shared__ float rp[256], rcn[256];
  int tid = threadIdx.x;
  float sp = 0.0f, sc = 0.0f;
  #pragma unroll
  for (int q = 0; q < NPART / 256; q++) {
    sp += pers[tid + 256 * q];
    sc += cnts[tid + 256 * q];
  }
  rp[tid] = sp; rcn[tid] = sc;
  __syncthreads();
  for (int s = 128; s > 0; s >>= 1) {
    if (tid < s) { rp[tid] += rp[tid + s]; rcn[tid] += rcn[tid + s]; }
    __syncthreads();
  }
  if (tid == 0) out[0] = rp[0] / fmaxf(rcn[0], 1.0f);
}

extern "C" void kernel_launch(void* const* d_in, const int* in_sizes, int n_in,
                              void* d_out, int out_size, void* d_ws, size_t ws_size,
                              hipStream_t stream) {
  const float* emb = (const float*)d_in[0];
  const int* labels = (const int*)d_in[1];
  char* ws = (char*)d_ws;
  float* sq      = (float*)(ws + 0);          // 32 KB
  float* ap2lo   = (float*)(ws + 32768);      // 32 KB
  float* ap2hi   = (float*)(ws + 65536);      // 32 KB
  int* posx      = (int*)(ws + 98304);        // 32 KB
  int* validf    = (int*)(ws + 131072);       // 32 KB
  float* pers    = (float*)(ws + 163840);     // 8 KB
  float* cnts    = (float*)(ws + 180224);     // 8 KB
  uint32_t* psb  = (uint32_t*)(ws + 262144);  // 512 KB
  int* psi       = (int*)(ws + 786432);       // 512 KB
  float* phd2    = (float*)(ws + 1310720);    // 512 KB
  int* phi       = (int*)(ws + 1835008);      // 512 KB
  uint32_t* chnk = (uint32_t*)(ws + 2359296); // 4 MB
  float* out     = (float*)d_out;

  // jax.random.key(42) -> split
  uint32_t A0, B0, A1, B1;
  tf2x32(0u, 42u, 0u, 2u, A0, B0);
  tf2x32(0u, 42u, 1u, 3u, A1, B1);
  uint32_t kp0 = A0, kp1 = A1, kn0 = B0, kn1 = B1;

  prep_kernel<<<512, 256, 0, stream>>>(emb, chnk, sq);
  pos_kernel<<<B, 256, 0, stream>>>(emb, labels, sq, kp0, kp1, posx, ap2lo, ap2hi, validf);
  main_kernel<<<dim3(32, NCHUNK), 256, 0, stream>>>(chnk, labels, sq, ap2lo, ap2hi,
                                                    kn0, kn1, psb, psi, phd2, phi);
  finalize_kernel<<<NPART, 256, 0, stream>>>(emb, posx, validf, psb, psi, phd2, phi,
                                             pers, cnts);
  reduce_kernel<<<1, 256, 0, stream>>>(pers, cnts, out);
}